// Round 9
// baseline (142.203 us; speedup 1.0000x reference)
//
#include <hip/hip_runtime.h>
#include <hip/hip_bf16.h>
#include <math.h>

#define TB 8
#define TT 2048
#define TD 64
#define TK 5
#define TPAD 12
#define EPSBN 1e-5f
#define UMAX 4096

#define ROWS 64          // mm1: output rows per block (2 waves x 32)
#define BAND 66          // ROWS + 2 halo
#define LROWS 198        // 3 bands

// mm2f geometry: 32 rows/block, 2 waves x 16 rows
#define ROWS2 32
#define BAND2 34
#define LROWS2 102       // 3 bands
#define SH8   816        // LROWS2 * 8 short8 per buffer
#define BUFB  13056      // LROWS2*64*2 bytes per buffer

typedef __attribute__((ext_vector_type(8))) short short8;
typedef __attribute__((ext_vector_type(4))) float f32x4;

// ws layout (float offsets)
#define OFF_S     0
#define OFF_SBF   1048576
#define OFF_R     1572864
#define OFF_IDX   1581056
#define OFF_W     1581096
#define OFF_WT1   1581136
#define OFF_WT2   1599568
#define OFF_H1    1618000
// end 6860880 floats = 27.4 MB

// ---------------- fused: trend/seasonal (sliding window) + weight repack ----------------
__global__ __launch_bounds__(256) void k_trend(const float* __restrict__ x,
                                               float* __restrict__ out, float* __restrict__ s,
                                               __hip_bfloat16* __restrict__ sbf,
                                               const float* __restrict__ w1, const float* __restrict__ w2,
                                               __hip_bfloat16* __restrict__ wt1, __hip_bfloat16* __restrict__ wt2)
{
    if (blockIdx.x >= 256) {
        int d = (blockIdx.x - 256) * 256 + threadIdx.x;
        if (d < 36864) {
            int j = d & 7, l = (d >> 3) & 63, nt = (d >> 9) & 3, kb = d >> 11;
            int tap = kb >> 1, half = kb & 1;
            int co = nt * 16 + (l & 15);
            int ci = half * 32 + (l >> 4) * 8 + j;
            int src = (co * 64 + ci) * 9 + tap;
            wt1[d] = __float2bfloat16(w1[src]);
            wt2[d] = __float2bfloat16(w2[src]);
        }
        return;
    }
    int gid = blockIdx.x * 256 + threadIdx.x;      // 65536 threads
    int c = gid & 63;
    int tblk = (gid >> 6) & 127;
    int b = gid >> 13;
    int t0 = tblk * 16;
    const float* base = x + (size_t)b * TT * TD + c;
    float sum = 0.f;
    for (int tt = t0 - TPAD; tt <= t0 + TPAD; ++tt)
        if (tt >= 0 && tt < TT) sum += base[(size_t)tt * TD];
    size_t o = (size_t)b * TT * TD + (size_t)t0 * TD + c;
    #pragma unroll
    for (int i = 0; i < 16; ++i) {
        int t = t0 + i;
        int lo = t - TPAD; if (lo < 0) lo = 0;
        int hi = t + TPAD; if (hi > TT - 1) hi = TT - 1;
        float tr = sum / (float)(hi - lo + 1);
        float xv = base[(size_t)t * TD];
        out[o] = xv + tr;
        float sv = xv - tr;
        s[o] = sv;
        sbf[o] = __float2bfloat16(sv);
        int addt = t + TPAD + 1, subt = t - TPAD;
        if (addt < TT) sum += base[(size_t)addt * TD];
        if (subt >= 0) sum -= base[(size_t)subt * TD];
        o += TD;
    }
}

// ---------------- circular autocorrelation, lags 1..1024 (f32, 16-lag register window) ----------------
__global__ __launch_bounds__(256) void k_autocorr(const float* __restrict__ s, float* __restrict__ r)
{
    int b = blockIdx.z;
    int l0 = blockIdx.x * 16 + 1;                  // lags l0..l0+15
    const float* sb = s + (size_t)b * TT * TD;
    int cg = (threadIdx.x & 15) * 4;
    int tg = threadIdx.x >> 4;
    int t0 = blockIdx.y * 1024 + tg * 64;
    const int RB = TD * 4;
    const int TTB = TT * TD * 4;
    float acc[16];
    #pragma unroll
    for (int j = 0; j < 16; ++j) acc[j] = 0.f;
    float4 win[16];
    int wi = t0 + l0; if (wi >= TT) wi -= TT;
    int woff = wi * RB + cg * 4;
    int aoff = t0 * RB + cg * 4;
    #pragma unroll
    for (int m = 0; m < 16; ++m) {
        win[m] = *(const float4*)((const char*)sb + woff);
        woff += RB; if (woff >= TTB) woff -= TTB;
    }
    for (int it = 0; it < 4; ++it) {
        #pragma unroll
        for (int jj = 0; jj < 16; ++jj) {
            float4 a = *(const float4*)((const char*)sb + aoff);
            aoff += RB;
            #pragma unroll
            for (int j = 0; j < 16; ++j) {
                float4 w = win[(jj + j) & 15];
                acc[j] = fmaf(a.x, w.x, acc[j]);
                acc[j] = fmaf(a.y, w.y, acc[j]);
                acc[j] = fmaf(a.z, w.z, acc[j]);
                acc[j] = fmaf(a.w, w.w, acc[j]);
            }
            win[jj] = *(const float4*)((const char*)sb + woff);
            woff += RB; if (woff >= TTB) woff -= TTB;
        }
    }
    __shared__ float red[16 * 256];
    #pragma unroll
    for (int j = 0; j < 16; ++j) red[j * 256 + threadIdx.x] = acc[j];
    __syncthreads();
    int j = threadIdx.x >> 4, i = threadIdx.x & 15;
    float v = 0.f;
    #pragma unroll
    for (int m = 0; m < 16; ++m) v += red[j * 256 + i + 16 * m];
    #pragma unroll
    for (int mask = 8; mask; mask >>= 1) v += __shfl_xor(v, mask);
    if (i == 0) atomicAdd(&r[(size_t)b * 1024 + (l0 - 1 + j)], v * (1.0f / 64.0f));
}

// ---------------- top-5 with symmetric-pair expansion + softmax ----------------
__global__ __launch_bounds__(256) void k_topk(const float* __restrict__ r,
                                              int* __restrict__ selidx, float* __restrict__ selw)
{
    int b = blockIdx.x;
    __shared__ float v[1024];
    __shared__ float redv[256]; __shared__ int redi[256];
    __shared__ int s_idx[6]; __shared__ float s_val[6]; __shared__ int slots;
    for (int i = threadIdx.x; i < 1024; i += 256) v[i] = r[(size_t)b * 1024 + i];
    if (threadIdx.x == 0) slots = 0;
    __syncthreads();
    for (int round = 0; round < 5; ++round) {
        if (slots >= 5) break;
        float bv = -INFINITY; int bi = 1 << 30;
        for (int i = threadIdx.x; i < 1024; i += 256) {
            float val = v[i];
            if (val > bv) { bv = val; bi = i; }
        }
        redv[threadIdx.x] = bv; redi[threadIdx.x] = bi;
        __syncthreads();
        for (int off = 128; off; off >>= 1) {
            if (threadIdx.x < off) {
                float ov = redv[threadIdx.x + off]; int oi = redi[threadIdx.x + off];
                float mv = redv[threadIdx.x];       int mi = redi[threadIdx.x];
                if (ov > mv || (ov == mv && oi < mi)) { redv[threadIdx.x] = ov; redi[threadIdx.x] = oi; }
            }
            __syncthreads();
        }
        if (threadIdx.x == 0) {
            int lag = redi[0] + 1; float val = redv[0];
            s_idx[slots] = lag; s_val[slots] = val; slots++;
            if (slots < 5 && lag < 1024) { s_idx[slots] = 2048 - lag; s_val[slots] = val; slots++; }
            v[lag - 1] = -INFINITY;
        }
        __syncthreads();
    }
    if (threadIdx.x == 0) {
        float mx = -INFINITY;
        for (int i = 0; i < 5; ++i) mx = fmaxf(mx, s_val[i]);
        float e[5], sum = 0.f;
        for (int i = 0; i < 5; ++i) { e[i] = expf(s_val[i] - mx); sum += e[i]; }
        for (int i = 0; i < 5; ++i) { selidx[b * TK + i] = s_idx[i]; selw[b * TK + i] = e[i] / sum; }
    }
}

// ---------------- conv1: LDS-staged 3-band halo + MFMA + BN1 + GELU -> h1 (bf16) ----------------
__global__ __launch_bounds__(128) void k_mm1(
    const short* __restrict__ s_bf, const short* __restrict__ wtp,
    const float* __restrict__ g1, const float* __restrict__ b1,
    const float* __restrict__ m1, const float* __restrict__ v1,
    const int* __restrict__ sel, __hip_bfloat16* __restrict__ h1)
{
    int b = blockIdx.z, k = blockIdx.y;
    int p = sel[b * TK + k];
    int cyc = (TT + p - 1) / p;
    int U = cyc * p;
    int u0 = blockIdx.x * ROWS;
    if (u0 >= U) return;
    __shared__ short As[LROWS * 64];

    const short* sb = s_bf + (size_t)b * TT * TD;
    for (int q = threadIdx.x; q < LROWS * 8; q += 128) {
        int row = q >> 3, ch = (q & 7) * 8;
        int band = row / BAND, i = row - band * BAND;
        int w = u0 + (band - 1) * p - 1 + i;
        int wc = min(max(w, 0), 2 * TT - 2);
        int v = (wc < TT) ? wc : (2 * TT - 2 - wc);
        int sr = (v + p) & (TT - 1);
        short8 d = *(const short8*)(sb + (size_t)sr * TD + ch);
        int off = (row * 128 + ch * 2) ^ ((row & 7) << 4);
        *(short8*)((char*)As + off) = d;
    }
    __syncthreads();

    int lane = threadIdx.x & 63;
    int wv = threadIdx.x >> 6;
    int lr = lane & 15;
    int kg = lane >> 4;
    bool inU[2], topf[2], botf[2], leftf[2], rightf[2];
    int lu[2];
    #pragma unroll
    for (int rs = 0; rs < 2; ++rs) {
        lu[rs] = wv * 32 + rs * 16 + lr;
        int u = u0 + lu[rs];
        inU[rs] = (u < U);
        int r = u / p, c = u - r * p;
        topf[rs] = (r == 0); botf[rs] = (r == cyc - 1);
        leftf[rs] = (c == 0); rightf[rs] = (c == p - 1);
    }
    f32x4 acc[2][4] = {};
    short8 zero = {};
    #pragma unroll
    for (int kb = 0; kb < 18; ++kb) {
        const int tap = kb >> 1, half = kb & 1;
        const int dr = tap / 3 - 1, dc = tap % 3 - 1;
        short8 a[2];
        #pragma unroll
        for (int rs = 0; rs < 2; ++rs) {
            int ldsrow = (dr + 1) * BAND + lu[rs] + 1 + dc;
            int off = (ldsrow * 128 + half * 64 + kg * 16) ^ ((ldsrow & 7) << 4);
            a[rs] = *(const short8*)((const char*)As + off);
            bool valid = inU[rs]
                       && !(dr == -1 && topf[rs]) && !(dr == 1 && botf[rs])
                       && !(dc == -1 && leftf[rs]) && !(dc == 1 && rightf[rs]);
            if (!valid) a[rs] = zero;
        }
        #pragma unroll
        for (int nt = 0; nt < 4; ++nt) {
            short8 bq = *(const short8*)(wtp + (size_t)(kb * 4 + nt) * 512 + lane * 8);
            #pragma unroll
            for (int rs = 0; rs < 2; ++rs)
                acc[rs][nt] = __builtin_amdgcn_mfma_f32_16x16x32_bf16(a[rs], bq, acc[rs][nt], 0, 0, 0);
        }
    }
    __hip_bfloat16* ho = h1 + (size_t)(b * TK + k) * (UMAX * TD);
    #pragma unroll
    for (int nt = 0; nt < 4; ++nt) {
        int co = nt * 16 + lr;
        float scale = g1[co] * rsqrtf(v1[co] + EPSBN);
        float bias = b1[co] - m1[co] * scale;
        #pragma unroll
        for (int rs = 0; rs < 2; ++rs) {
            int ub = u0 + wv * 32 + rs * 16 + kg * 4;
            #pragma unroll
            for (int q = 0; q < 4; ++q) {
                int u = ub + q;
                if (u < U) {
                    float z = acc[rs][nt][q] * scale + bias;
                    float ge = 0.5f * z * (1.0f + erff(z * 0.70710678118654752f));
                    ho[(size_t)u * TD + co] = __float2bfloat16(ge);
                }
            }
        }
    }
}

// ---------------- conv2 fused over k: double-buffered LDS, accT = sum_k w_k conv_k ----------------
// out += sum_k w_k gval_k + scale*accT + bias   (sum w_k = 1; block owns rows exclusively -> no atomics)
__global__ __launch_bounds__(128) void k_mm2f(
    const short* __restrict__ h1, const short* __restrict__ wtp,
    const float* __restrict__ s,
    const float* __restrict__ g2, const float* __restrict__ b2,
    const float* __restrict__ m2, const float* __restrict__ v2,
    const int* __restrict__ sel, const float* __restrict__ selw,
    float* __restrict__ out)
{
    int b = blockIdx.y;
    int u0 = blockIdx.x * ROWS2;                      // < 2048
    int tid = threadIdx.x;
    __shared__ short As[2 * LROWS2 * 64];

    int lane = tid & 63, wv = tid >> 6, lr = lane & 15, kg = lane >> 4;
    int lu = wv * 16 + lr;
    int u = u0 + lu;
    const float* sb = s + (size_t)b * TT * TD;

    f32x4 accT[4] = {};
    float gacc[4][4] = {};
    short8 sreg[7];
    short8 zero = {};

    // prologue: stage phase 0 into buffer 0
    {
        int p0 = sel[b * TK];
        const short* hb = h1 + (size_t)(b * TK) * (UMAX * TD);
        #pragma unroll
        for (int it = 0; it < 7; ++it) {
            int q = tid + it * 128;
            if (q < SH8) {
                int row = q >> 3, ch = (q & 7) * 8;
                int band = row / BAND2, i = row - band * BAND2;
                int w = u0 + (band - 1) * p0 - 1 + i;
                int wc = min(max(w, 0), UMAX - 1);
                sreg[it] = *(const short8*)(hb + (size_t)wc * TD + ch);
            }
        }
        #pragma unroll
        for (int it = 0; it < 7; ++it) {
            int q = tid + it * 128;
            if (q < SH8) {
                int row = q >> 3, ch = (q & 7) * 8;
                int off = (row * 128 + ch * 2) ^ ((row & 7) << 4);
                *(short8*)((char*)As + off) = sreg[it];
            }
        }
    }
    __syncthreads();

    for (int k = 0; k < TK; ++k) {
        int p = sel[b * TK + k];
        float wk = selw[b * TK + k];
        int cyc = (TT + p - 1) / p;
        // T14: issue next phase's global loads before this phase's compute
        if (k < TK - 1) {
            int pn = sel[b * TK + k + 1];
            const short* hb = h1 + (size_t)(b * TK + k + 1) * (UMAX * TD);
            #pragma unroll
            for (int it = 0; it < 7; ++it) {
                int q = tid + it * 128;
                if (q < SH8) {
                    int row = q >> 3, ch = (q & 7) * 8;
                    int band = row / BAND2, i = row - band * BAND2;
                    int w = u0 + (band - 1) * pn - 1 + i;
                    int wc = min(max(w, 0), UMAX - 1);
                    sreg[it] = *(const short8*)(hb + (size_t)wc * TD + ch);
                }
            }
        }
        // compute phase k from buffer k&1
        const char* Ab = (const char*)As + (k & 1) * BUFB;
        int r = u / p, c = u - r * p;
        bool topf = (r == 0), botf = (r == cyc - 1), leftf = (c == 0), rightf = (c == p - 1);
        f32x4 accP[4] = {};
        #pragma unroll
        for (int kb = 0; kb < 18; ++kb) {
            const int tap = kb >> 1, half = kb & 1;
            const int dr = tap / 3 - 1, dc = tap % 3 - 1;
            int ldsrow = (dr + 1) * BAND2 + lu + 1 + dc;
            int off = (ldsrow * 128 + half * 64 + kg * 16) ^ ((ldsrow & 7) << 4);
            short8 a = *(const short8*)(Ab + off);
            bool valid = !(dr == -1 && topf) && !(dr == 1 && botf)
                       && !(dc == -1 && leftf) && !(dc == 1 && rightf);
            if (!valid) a = zero;
            #pragma unroll
            for (int nt = 0; nt < 4; ++nt) {
                short8 bq = *(const short8*)(wtp + (size_t)(kb * 4 + nt) * 512 + lane * 8);
                accP[nt] = __builtin_amdgcn_mfma_f32_16x16x32_bf16(a, bq, accP[nt], 0, 0, 0);
            }
        }
        #pragma unroll
        for (int nt = 0; nt < 4; ++nt)
            #pragma unroll
            for (int e = 0; e < 4; ++e) accT[nt][e] += wk * accP[nt][e];
        #pragma unroll
        for (int q = 0; q < 4; ++q) {
            int uo = u0 + wv * 16 + kg * 4 + q;
            int sr = (uo + p) & (TT - 1);
            #pragma unroll
            for (int nt = 0; nt < 4; ++nt)
                gacc[nt][q] = fmaf(wk, sb[(size_t)sr * TD + nt * 16 + lr], gacc[nt][q]);
        }
        __syncthreads();
        if (k < TK - 1) {
            char* Aw = (char*)As + ((k + 1) & 1) * BUFB;
            #pragma unroll
            for (int it = 0; it < 7; ++it) {
                int q = tid + it * 128;
                if (q < SH8) {
                    int row = q >> 3, ch = (q & 7) * 8;
                    int off = (row * 128 + ch * 2) ^ ((row & 7) << 4);
                    *(short8*)(Aw + off) = sreg[it];
                }
            }
            __syncthreads();
        }
    }

    float* ob = out + (size_t)b * TT * TD;
    #pragma unroll
    for (int nt = 0; nt < 4; ++nt) {
        int co = nt * 16 + lr;
        float scale = g2[co] * rsqrtf(v2[co] + EPSBN);
        float bias = b2[co] - m2[co] * scale;
        #pragma unroll
        for (int q = 0; q < 4; ++q) {
            int uo = u0 + wv * 16 + kg * 4 + q;
            size_t idx = (size_t)uo * TD + co;
            ob[idx] = ob[idx] + gacc[nt][q] + scale * accT[nt][q] + bias;
        }
    }
}

extern "C" void kernel_launch(void* const* d_in, const int* in_sizes, int n_in,
                              void* d_out, int out_size, void* d_ws, size_t ws_size,
                              hipStream_t stream)
{
    const float* x  = (const float*)d_in[0];
    const float* w1 = (const float*)d_in[1];
    const float* w2 = (const float*)d_in[2];
    const float* g1 = (const float*)d_in[3];
    const float* b1 = (const float*)d_in[4];
    const float* m1 = (const float*)d_in[5];
    const float* v1 = (const float*)d_in[6];
    const float* g2 = (const float*)d_in[7];
    const float* b2 = (const float*)d_in[8];
    const float* m2 = (const float*)d_in[9];
    const float* v2 = (const float*)d_in[10];

    float* ws    = (float*)d_ws;
    float* s     = ws + OFF_S;
    __hip_bfloat16* sbf = (__hip_bfloat16*)(ws + OFF_SBF);
    float* r     = ws + OFF_R;
    int*   sel   = (int*)(ws + OFF_IDX);
    float* selw  = ws + OFF_W;
    __hip_bfloat16* wt1 = (__hip_bfloat16*)(ws + OFF_WT1);
    __hip_bfloat16* wt2 = (__hip_bfloat16*)(ws + OFF_WT2);
    __hip_bfloat16* h1  = (__hip_bfloat16*)(ws + OFF_H1);
    float* out   = (float*)d_out;

    k_trend   <<<dim3(400),         dim3(256), 0, stream>>>(x, out, s, sbf, w1, w2, wt1, wt2);
    hipMemsetAsync(r, 0, (size_t)TB * 1024 * sizeof(float), stream);
    k_autocorr<<<dim3(64, 2, TB),   dim3(256), 0, stream>>>(s, r);
    k_topk    <<<dim3(TB),          dim3(256), 0, stream>>>(r, sel, selw);
    k_mm1     <<<dim3(64, TK, TB),  dim3(128), 0, stream>>>((const short*)sbf, (const short*)wt1,
                                                            g1, b1, m1, v1, sel, h1);
    k_mm2f    <<<dim3(64, TB),      dim3(128), 0, stream>>>((const short*)h1, (const short*)wt2, s,
                                                            g2, b2, m2, v2, sel, selw, out);
}

// Round 10
// 121.787 us; speedup vs baseline: 1.1676x; 1.1676x over previous
//
#include <hip/hip_runtime.h>
#include <hip/hip_bf16.h>
#include <math.h>

#define TB 8
#define TT 2048
#define TD 64
#define TK 5
#define TPAD 12
#define EPSBN 1e-5f
#define UMAX 4096

#define ROWS 64          // mm1: output rows per block (4 waves x 16)
#define BAND 66          // ROWS + 2 halo
#define LROWS 198        // 3 bands

// mm2f geometry: 16 rows/block, 4 waves; wave = 16u x 16co
#define ROWS2 16
#define BAND2 18
#define LROWS2 54        // 3 bands
#define SH8   432        // LROWS2 * 8 short8 per buffer
#define BUFB  6912       // LROWS2*64*2 bytes per buffer

typedef __attribute__((ext_vector_type(8))) short short8;
typedef __attribute__((ext_vector_type(4))) float f32x4;

// ws layout (float offsets)
#define OFF_S     0
#define OFF_SBF   1048576
#define OFF_R     1572864
#define OFF_IDX   1581056
#define OFF_W     1581096
#define OFF_WT1   1581136
#define OFF_WT2   1599568
#define OFF_H1    1618000
// end 6860880 floats = 27.4 MB

// ---------------- fused: trend/seasonal (sliding window) + weight repack ----------------
__global__ __launch_bounds__(256) void k_trend(const float* __restrict__ x,
                                               float* __restrict__ out, float* __restrict__ s,
                                               __hip_bfloat16* __restrict__ sbf,
                                               const float* __restrict__ w1, const float* __restrict__ w2,
                                               __hip_bfloat16* __restrict__ wt1, __hip_bfloat16* __restrict__ wt2)
{
    if (blockIdx.x >= 256) {
        int d = (blockIdx.x - 256) * 256 + threadIdx.x;
        if (d < 36864) {
            int j = d & 7, l = (d >> 3) & 63, nt = (d >> 9) & 3, kb = d >> 11;
            int tap = kb >> 1, half = kb & 1;
            int co = nt * 16 + (l & 15);
            int ci = half * 32 + (l >> 4) * 8 + j;
            int src = (co * 64 + ci) * 9 + tap;
            wt1[d] = __float2bfloat16(w1[src]);
            wt2[d] = __float2bfloat16(w2[src]);
        }
        return;
    }
    int gid = blockIdx.x * 256 + threadIdx.x;      // 65536 threads
    int c = gid & 63;
    int tblk = (gid >> 6) & 127;
    int b = gid >> 13;
    int t0 = tblk * 16;
    const float* base = x + (size_t)b * TT * TD + c;
    float sum = 0.f;
    for (int tt = t0 - TPAD; tt <= t0 + TPAD; ++tt)
        if (tt >= 0 && tt < TT) sum += base[(size_t)tt * TD];
    size_t o = (size_t)b * TT * TD + (size_t)t0 * TD + c;
    #pragma unroll
    for (int i = 0; i < 16; ++i) {
        int t = t0 + i;
        int lo = t - TPAD; if (lo < 0) lo = 0;
        int hi = t + TPAD; if (hi > TT - 1) hi = TT - 1;
        float tr = sum / (float)(hi - lo + 1);
        float xv = base[(size_t)t * TD];
        out[o] = xv + tr;
        float sv = xv - tr;
        s[o] = sv;
        sbf[o] = __float2bfloat16(sv);
        int addt = t + TPAD + 1, subt = t - TPAD;
        if (addt < TT) sum += base[(size_t)addt * TD];
        if (subt >= 0) sum -= base[(size_t)subt * TD];
        o += TD;
    }
}

// ---------------- circular autocorrelation, lags 1..1024 (f32, 16-lag register window) ----------------
__global__ __launch_bounds__(256) void k_autocorr(const float* __restrict__ s, float* __restrict__ r)
{
    int b = blockIdx.z;
    int l0 = blockIdx.x * 16 + 1;                  // lags l0..l0+15
    const float* sb = s + (size_t)b * TT * TD;
    int cg = (threadIdx.x & 15) * 4;
    int tg = threadIdx.x >> 4;
    int t0 = blockIdx.y * 1024 + tg * 64;
    const int RB = TD * 4;
    const int TTB = TT * TD * 4;
    float acc[16];
    #pragma unroll
    for (int j = 0; j < 16; ++j) acc[j] = 0.f;
    float4 win[16];
    int wi = t0 + l0; if (wi >= TT) wi -= TT;
    int woff = wi * RB + cg * 4;
    int aoff = t0 * RB + cg * 4;
    #pragma unroll
    for (int m = 0; m < 16; ++m) {
        win[m] = *(const float4*)((const char*)sb + woff);
        woff += RB; if (woff >= TTB) woff -= TTB;
    }
    for (int it = 0; it < 4; ++it) {
        #pragma unroll
        for (int jj = 0; jj < 16; ++jj) {
            float4 a = *(const float4*)((const char*)sb + aoff);
            aoff += RB;
            #pragma unroll
            for (int j = 0; j < 16; ++j) {
                float4 w = win[(jj + j) & 15];
                acc[j] = fmaf(a.x, w.x, acc[j]);
                acc[j] = fmaf(a.y, w.y, acc[j]);
                acc[j] = fmaf(a.z, w.z, acc[j]);
                acc[j] = fmaf(a.w, w.w, acc[j]);
            }
            win[jj] = *(const float4*)((const char*)sb + woff);
            woff += RB; if (woff >= TTB) woff -= TTB;
        }
    }
    __shared__ float red[16 * 256];
    #pragma unroll
    for (int j = 0; j < 16; ++j) red[j * 256 + threadIdx.x] = acc[j];
    __syncthreads();
    int j = threadIdx.x >> 4, i = threadIdx.x & 15;
    float v = 0.f;
    #pragma unroll
    for (int m = 0; m < 16; ++m) v += red[j * 256 + i + 16 * m];
    #pragma unroll
    for (int mask = 8; mask; mask >>= 1) v += __shfl_xor(v, mask);
    if (i == 0) atomicAdd(&r[(size_t)b * 1024 + (l0 - 1 + j)], v * (1.0f / 64.0f));
}

// ---------------- top-5 with symmetric-pair expansion + softmax ----------------
__global__ __launch_bounds__(256) void k_topk(const float* __restrict__ r,
                                              int* __restrict__ selidx, float* __restrict__ selw)
{
    int b = blockIdx.x;
    __shared__ float v[1024];
    __shared__ float redv[256]; __shared__ int redi[256];
    __shared__ int s_idx[6]; __shared__ float s_val[6]; __shared__ int slots;
    for (int i = threadIdx.x; i < 1024; i += 256) v[i] = r[(size_t)b * 1024 + i];
    if (threadIdx.x == 0) slots = 0;
    __syncthreads();
    for (int round = 0; round < 5; ++round) {
        if (slots >= 5) break;
        float bv = -INFINITY; int bi = 1 << 30;
        for (int i = threadIdx.x; i < 1024; i += 256) {
            float val = v[i];
            if (val > bv) { bv = val; bi = i; }
        }
        redv[threadIdx.x] = bv; redi[threadIdx.x] = bi;
        __syncthreads();
        for (int off = 128; off; off >>= 1) {
            if (threadIdx.x < off) {
                float ov = redv[threadIdx.x + off]; int oi = redi[threadIdx.x + off];
                float mv = redv[threadIdx.x];       int mi = redi[threadIdx.x];
                if (ov > mv || (ov == mv && oi < mi)) { redv[threadIdx.x] = ov; redi[threadIdx.x] = oi; }
            }
            __syncthreads();
        }
        if (threadIdx.x == 0) {
            int lag = redi[0] + 1; float val = redv[0];
            s_idx[slots] = lag; s_val[slots] = val; slots++;
            if (slots < 5 && lag < 1024) { s_idx[slots] = 2048 - lag; s_val[slots] = val; slots++; }
            v[lag - 1] = -INFINITY;
        }
        __syncthreads();
    }
    if (threadIdx.x == 0) {
        float mx = -INFINITY;
        for (int i = 0; i < 5; ++i) mx = fmaxf(mx, s_val[i]);
        float e[5], sum = 0.f;
        for (int i = 0; i < 5; ++i) { e[i] = expf(s_val[i] - mx); sum += e[i]; }
        for (int i = 0; i < 5; ++i) { selidx[b * TK + i] = s_idx[i]; selw[b * TK + i] = e[i] / sum; }
    }
}

// ---------------- conv1: 4-wave blocks, wave = 16u x 64co; LDS halo + MFMA + BN1 + GELU ----------------
__global__ __launch_bounds__(256) void k_mm1(
    const short* __restrict__ s_bf, const short* __restrict__ wtp,
    const float* __restrict__ g1, const float* __restrict__ b1,
    const float* __restrict__ m1, const float* __restrict__ v1,
    const int* __restrict__ sel, __hip_bfloat16* __restrict__ h1)
{
    int b = blockIdx.z, k = blockIdx.y;
    int p = sel[b * TK + k];
    int cyc = (TT + p - 1) / p;
    int U = cyc * p;
    int u0 = blockIdx.x * ROWS;
    if (u0 >= U) return;
    __shared__ short As[LROWS * 64];

    const short* sb = s_bf + (size_t)b * TT * TD;
    for (int q = threadIdx.x; q < LROWS * 8; q += 256) {
        int row = q >> 3, ch = (q & 7) * 8;
        int band = row / BAND, i = row - band * BAND;
        int w = u0 + (band - 1) * p - 1 + i;
        int wc = min(max(w, 0), 2 * TT - 2);
        int v = (wc < TT) ? wc : (2 * TT - 2 - wc);
        int sr = (v + p) & (TT - 1);
        short8 d = *(const short8*)(sb + (size_t)sr * TD + ch);
        int off = (row * 128 + ch * 2) ^ ((row & 7) << 4);
        *(short8*)((char*)As + off) = d;
    }
    __syncthreads();

    int lane = threadIdx.x & 63;
    int wv = threadIdx.x >> 6;
    int lr = lane & 15;
    int kg = lane >> 4;
    int lu = wv * 16 + lr;
    int u = u0 + lu;
    bool inU = (u < U);
    int r = u / p, c = u - r * p;
    bool topf = (r == 0), botf = (r == cyc - 1), leftf = (c == 0), rightf = (c == p - 1);

    f32x4 acc[4] = {};
    short8 zero = {};
    #pragma unroll
    for (int kb = 0; kb < 18; ++kb) {
        const int tap = kb >> 1, half = kb & 1;
        const int dr = tap / 3 - 1, dc = tap % 3 - 1;
        int ldsrow = (dr + 1) * BAND + lu + 1 + dc;
        int off = (ldsrow * 128 + half * 64 + kg * 16) ^ ((ldsrow & 7) << 4);
        short8 a = *(const short8*)((const char*)As + off);
        bool valid = inU
                   && !(dr == -1 && topf) && !(dr == 1 && botf)
                   && !(dc == -1 && leftf) && !(dc == 1 && rightf);
        if (!valid) a = zero;
        #pragma unroll
        for (int nt = 0; nt < 4; ++nt) {
            short8 bq = *(const short8*)(wtp + (size_t)(kb * 4 + nt) * 512 + lane * 8);
            acc[nt] = __builtin_amdgcn_mfma_f32_16x16x32_bf16(a, bq, acc[nt], 0, 0, 0);
        }
    }
    __hip_bfloat16* ho = h1 + (size_t)(b * TK + k) * (UMAX * TD);
    #pragma unroll
    for (int nt = 0; nt < 4; ++nt) {
        int co = nt * 16 + lr;
        float scale = g1[co] * rsqrtf(v1[co] + EPSBN);
        float bias = b1[co] - m1[co] * scale;
        #pragma unroll
        for (int q = 0; q < 4; ++q) {
            int uo = u0 + wv * 16 + kg * 4 + q;
            if (uo < U) {
                float z = acc[nt][q] * scale + bias;
                float ge = 0.5f * z * (1.0f + erff(z * 0.70710678118654752f));
                ho[(size_t)uo * TD + co] = __float2bfloat16(ge);
            }
        }
    }
}

// ---------------- conv2 fused over k: 4-wave blocks (wave = 16u x 16co), dbuf LDS, no atomics ----------------
__global__ __launch_bounds__(256) void k_mm2f(
    const short* __restrict__ h1, const short* __restrict__ wtp,
    const float* __restrict__ s,
    const float* __restrict__ g2, const float* __restrict__ b2,
    const float* __restrict__ m2, const float* __restrict__ v2,
    const int* __restrict__ sel, const float* __restrict__ selw,
    float* __restrict__ out)
{
    int b = blockIdx.y;
    int u0 = blockIdx.x * ROWS2;                      // < 2048
    int tid = threadIdx.x;
    __shared__ short As[2 * LROWS2 * 64];

    int lane = tid & 63, wv = tid >> 6, lr = lane & 15, kg = lane >> 4;
    int u = u0 + lr;
    const float* sb = s + (size_t)b * TT * TD;

    f32x4 accT = {};
    float gacc[4] = {0.f, 0.f, 0.f, 0.f};
    short8 sreg[2];
    short8 zero = {};

    // prologue: stage phase 0 into buffer 0
    {
        int p0 = sel[b * TK];
        const short* hb = h1 + (size_t)(b * TK) * (UMAX * TD);
        #pragma unroll
        for (int it = 0; it < 2; ++it) {
            int q = tid + it * 256;
            if (q < SH8) {
                int row = q >> 3, ch = (q & 7) * 8;
                int band = row / BAND2, i = row - band * BAND2;
                int w = u0 + (band - 1) * p0 - 1 + i;
                int wc = min(max(w, 0), UMAX - 1);
                short8 d = *(const short8*)(hb + (size_t)wc * TD + ch);
                int off = (row * 128 + ch * 2) ^ ((row & 7) << 4);
                *(short8*)((char*)As + off) = d;
            }
        }
    }
    __syncthreads();

    for (int k = 0; k < TK; ++k) {
        int p = sel[b * TK + k];
        float wk = selw[b * TK + k];
        int cyc = (TT + p - 1) / p;
        // T14: issue next phase's global loads before this phase's compute
        if (k < TK - 1) {
            int pn = sel[b * TK + k + 1];
            const short* hb = h1 + (size_t)(b * TK + k + 1) * (UMAX * TD);
            #pragma unroll
            for (int it = 0; it < 2; ++it) {
                int q = tid + it * 256;
                if (q < SH8) {
                    int row = q >> 3, ch = (q & 7) * 8;
                    int band = row / BAND2, i = row - band * BAND2;
                    int w = u0 + (band - 1) * pn - 1 + i;
                    int wc = min(max(w, 0), UMAX - 1);
                    sreg[it] = *(const short8*)(hb + (size_t)wc * TD + ch);
                }
            }
        }
        // compute phase k from buffer k&1
        const char* Ab = (const char*)As + (k & 1) * BUFB;
        int r = u / p, c = u - r * p;
        bool topf = (r == 0), botf = (r == cyc - 1), leftf = (c == 0), rightf = (c == p - 1);
        f32x4 accP[2] = {};
        #pragma unroll
        for (int kb = 0; kb < 18; ++kb) {
            const int tap = kb >> 1, half = kb & 1;
            const int dr = tap / 3 - 1, dc = tap % 3 - 1;
            int ldsrow = (dr + 1) * BAND2 + lr + 1 + dc;
            int off = (ldsrow * 128 + half * 64 + kg * 16) ^ ((ldsrow & 7) << 4);
            short8 a = *(const short8*)(Ab + off);
            bool valid = !(dr == -1 && topf) && !(dr == 1 && botf)
                       && !(dc == -1 && leftf) && !(dc == 1 && rightf);
            if (!valid) a = zero;
            short8 bq = *(const short8*)(wtp + (size_t)(kb * 4 + wv) * 512 + lane * 8);
            accP[kb & 1] = __builtin_amdgcn_mfma_f32_16x16x32_bf16(a, bq, accP[kb & 1], 0, 0, 0);
        }
        #pragma unroll
        for (int e = 0; e < 4; ++e) accT[e] += wk * (accP[0][e] + accP[1][e]);
        #pragma unroll
        for (int q = 0; q < 4; ++q) {
            int uo = u0 + kg * 4 + q;
            int sr = (uo + p) & (TT - 1);
            gacc[q] = fmaf(wk, sb[(size_t)sr * TD + wv * 16 + lr], gacc[q]);
        }
        __syncthreads();
        if (k < TK - 1) {
            char* Aw = (char*)As + ((k + 1) & 1) * BUFB;
            #pragma unroll
            for (int it = 0; it < 2; ++it) {
                int q = tid + it * 256;
                if (q < SH8) {
                    int row = q >> 3, ch = (q & 7) * 8;
                    int off = (row * 128 + ch * 2) ^ ((row & 7) << 4);
                    *(short8*)(Aw + off) = sreg[it];
                }
            }
            __syncthreads();
        }
    }

    float* ob = out + (size_t)b * TT * TD;
    int co = wv * 16 + lr;
    float scale = g2[co] * rsqrtf(v2[co] + EPSBN);
    float bias = b2[co] - m2[co] * scale;
    #pragma unroll
    for (int q = 0; q < 4; ++q) {
        int uo = u0 + kg * 4 + q;
        size_t idx = (size_t)uo * TD + co;
        ob[idx] = ob[idx] + gacc[q] + scale * accT[q] + bias;
    }
}

extern "C" void kernel_launch(void* const* d_in, const int* in_sizes, int n_in,
                              void* d_out, int out_size, void* d_ws, size_t ws_size,
                              hipStream_t stream)
{
    const float* x  = (const float*)d_in[0];
    const float* w1 = (const float*)d_in[1];
    const float* w2 = (const float*)d_in[2];
    const float* g1 = (const float*)d_in[3];
    const float* b1 = (const float*)d_in[4];
    const float* m1 = (const float*)d_in[5];
    const float* v1 = (const float*)d_in[6];
    const float* g2 = (const float*)d_in[7];
    const float* b2 = (const float*)d_in[8];
    const float* m2 = (const float*)d_in[9];
    const float* v2 = (const float*)d_in[10];

    float* ws    = (float*)d_ws;
    float* s     = ws + OFF_S;
    __hip_bfloat16* sbf = (__hip_bfloat16*)(ws + OFF_SBF);
    float* r     = ws + OFF_R;
    int*   sel   = (int*)(ws + OFF_IDX);
    float* selw  = ws + OFF_W;
    __hip_bfloat16* wt1 = (__hip_bfloat16*)(ws + OFF_WT1);
    __hip_bfloat16* wt2 = (__hip_bfloat16*)(ws + OFF_WT2);
    __hip_bfloat16* h1  = (__hip_bfloat16*)(ws + OFF_H1);
    float* out   = (float*)d_out;

    k_trend   <<<dim3(400),         dim3(256), 0, stream>>>(x, out, s, sbf, w1, w2, wt1, wt2);
    hipMemsetAsync(r, 0, (size_t)TB * 1024 * sizeof(float), stream);
    k_autocorr<<<dim3(64, 2, TB),   dim3(256), 0, stream>>>(s, r);
    k_topk    <<<dim3(TB),          dim3(256), 0, stream>>>(r, sel, selw);
    k_mm1     <<<dim3(64, TK, TB),  dim3(256), 0, stream>>>((const short*)sbf, (const short*)wt1,
                                                            g1, b1, m1, v1, sel, h1);
    k_mm2f    <<<dim3(128, TB),     dim3(256), 0, stream>>>((const short*)h1, (const short*)wt2, s,
                                                            g2, b2, m2, v2, sel, selw, out);
}

// Round 11
// 119.838 us; speedup vs baseline: 1.1866x; 1.0163x over previous
//
#include <hip/hip_runtime.h>
#include <hip/hip_bf16.h>
#include <math.h>

#define TB 8
#define TT 2048
#define TD 64
#define TK 5
#define TPAD 12
#define EPSBN 1e-5f
#define UMAX 4096

#define ROWS 64          // mm1: output rows per block (4 waves x 16)
#define BAND 66          // ROWS + 2 halo
#define LROWS 198        // 3 bands

// mm2f geometry: 16 rows/block, 4 waves; wave = 16u x 16co
#define ROWS2 16
#define BAND2 18
#define LROWS2 54        // 3 bands
#define SH8   432        // LROWS2 * 8 short8 per buffer
#define BUFB  6912       // LROWS2*64*2 bytes per buffer

typedef __attribute__((ext_vector_type(8))) short short8;
typedef __attribute__((ext_vector_type(4))) float f32x4;

// ws layout (float offsets)
#define OFF_S     0
#define OFF_SBF   1048576
#define OFF_R     1572864
#define OFF_IDX   1581056
#define OFF_W     1581096
#define OFF_WT1   1581136
#define OFF_WT2   1599568
#define OFF_H1    1618000
// end 6860880 floats = 27.4 MB

// ---------------- fused: trend/seasonal (sliding window) + weight repack + r zero ----------------
__global__ __launch_bounds__(256) void k_trend(const float* __restrict__ x,
                                               float* __restrict__ out, float* __restrict__ s,
                                               __hip_bfloat16* __restrict__ sbf,
                                               const float* __restrict__ w1, const float* __restrict__ w2,
                                               __hip_bfloat16* __restrict__ wt1, __hip_bfloat16* __restrict__ wt2,
                                               float* __restrict__ r)
{
    if (blockIdx.x >= 256) {
        int d = (blockIdx.x - 256) * 256 + threadIdx.x;
        if (d < TB * 1024) r[d] = 0.f;             // zero autocorr accumulator (replaces memset node)
        if (d < 36864) {
            int j = d & 7, l = (d >> 3) & 63, nt = (d >> 9) & 3, kb = d >> 11;
            int tap = kb >> 1, half = kb & 1;
            int co = nt * 16 + (l & 15);
            int ci = half * 32 + (l >> 4) * 8 + j;
            int src = (co * 64 + ci) * 9 + tap;
            wt1[d] = __float2bfloat16(w1[src]);
            wt2[d] = __float2bfloat16(w2[src]);
        }
        return;
    }
    int gid = blockIdx.x * 256 + threadIdx.x;      // 65536 threads
    int c = gid & 63;
    int tblk = (gid >> 6) & 127;
    int b = gid >> 13;
    int t0 = tblk * 16;
    const float* base = x + (size_t)b * TT * TD + c;
    float sum = 0.f;
    for (int tt = t0 - TPAD; tt <= t0 + TPAD; ++tt)
        if (tt >= 0 && tt < TT) sum += base[(size_t)tt * TD];
    size_t o = (size_t)b * TT * TD + (size_t)t0 * TD + c;
    #pragma unroll
    for (int i = 0; i < 16; ++i) {
        int t = t0 + i;
        int lo = t - TPAD; if (lo < 0) lo = 0;
        int hi = t + TPAD; if (hi > TT - 1) hi = TT - 1;
        float tr = sum / (float)(hi - lo + 1);
        float xv = base[(size_t)t * TD];
        out[o] = xv + tr;
        float sv = xv - tr;
        s[o] = sv;
        sbf[o] = __float2bfloat16(sv);
        int addt = t + TPAD + 1, subt = t - TPAD;
        if (addt < TT) sum += base[(size_t)addt * TD];
        if (subt >= 0) sum -= base[(size_t)subt * TD];
        o += TD;
    }
}

// ---------------- circular autocorrelation, lags 1..1024 (f32, 16-lag window, a-prefetch) ----------------
__global__ __launch_bounds__(256) void k_autocorr(const float* __restrict__ s, float* __restrict__ r)
{
    int b = blockIdx.z;
    int l0 = blockIdx.x * 16 + 1;                  // lags l0..l0+15
    const float* sb = s + (size_t)b * TT * TD;
    int cg = (threadIdx.x & 15) * 4;
    int tg = threadIdx.x >> 4;
    int t0 = blockIdx.y * 1024 + tg * 64;
    const int RB = TD * 4;
    const int TTB = TT * TD * 4;
    float acc[16];
    #pragma unroll
    for (int j = 0; j < 16; ++j) acc[j] = 0.f;
    float4 win[16];
    int wi = t0 + l0; if (wi >= TT) wi -= TT;
    int woff = wi * RB + cg * 4;
    int aoff = t0 * RB + cg * 4;
    #pragma unroll
    for (int m = 0; m < 16; ++m) {
        win[m] = *(const float4*)((const char*)sb + woff);
        woff += RB; if (woff >= TTB) woff -= TTB;
    }
    float4 a_pf = *(const float4*)((const char*)sb + aoff);
    aoff += RB;
    for (int it = 0; it < 4; ++it) {
        #pragma unroll
        for (int jj = 0; jj < 16; ++jj) {
            float4 a = a_pf;
            a_pf = *(const float4*)((const char*)sb + aoff);   // 1-deep prefetch (last one over-reads 256B, unused)
            aoff += RB;
            #pragma unroll
            for (int j = 0; j < 16; ++j) {
                float4 w = win[(jj + j) & 15];
                acc[j] = fmaf(a.x, w.x, acc[j]);
                acc[j] = fmaf(a.y, w.y, acc[j]);
                acc[j] = fmaf(a.z, w.z, acc[j]);
                acc[j] = fmaf(a.w, w.w, acc[j]);
            }
            win[jj] = *(const float4*)((const char*)sb + woff);
            woff += RB; if (woff >= TTB) woff -= TTB;
        }
    }
    __shared__ float red[16 * 256];
    #pragma unroll
    for (int j = 0; j < 16; ++j) red[j * 256 + threadIdx.x] = acc[j];
    __syncthreads();
    int j = threadIdx.x >> 4, i = threadIdx.x & 15;
    float v = 0.f;
    #pragma unroll
    for (int m = 0; m < 16; ++m) v += red[j * 256 + i + 16 * m];
    #pragma unroll
    for (int mask = 8; mask; mask >>= 1) v += __shfl_xor(v, mask);
    if (i == 0) atomicAdd(&r[(size_t)b * 1024 + (l0 - 1 + j)], v * (1.0f / 64.0f));
}

// ---------------- top-5 with symmetric-pair expansion + softmax ----------------
__global__ __launch_bounds__(256) void k_topk(const float* __restrict__ r,
                                              int* __restrict__ selidx, float* __restrict__ selw)
{
    int b = blockIdx.x;
    __shared__ float v[1024];
    __shared__ float redv[256]; __shared__ int redi[256];
    __shared__ int s_idx[6]; __shared__ float s_val[6]; __shared__ int slots;
    for (int i = threadIdx.x; i < 1024; i += 256) v[i] = r[(size_t)b * 1024 + i];
    if (threadIdx.x == 0) slots = 0;
    __syncthreads();
    for (int round = 0; round < 5; ++round) {
        if (slots >= 5) break;
        float bv = -INFINITY; int bi = 1 << 30;
        for (int i = threadIdx.x; i < 1024; i += 256) {
            float val = v[i];
            if (val > bv) { bv = val; bi = i; }
        }
        redv[threadIdx.x] = bv; redi[threadIdx.x] = bi;
        __syncthreads();
        for (int off = 128; off; off >>= 1) {
            if (threadIdx.x < off) {
                float ov = redv[threadIdx.x + off]; int oi = redi[threadIdx.x + off];
                float mv = redv[threadIdx.x];       int mi = redi[threadIdx.x];
                if (ov > mv || (ov == mv && oi < mi)) { redv[threadIdx.x] = ov; redi[threadIdx.x] = oi; }
            }
            __syncthreads();
        }
        if (threadIdx.x == 0) {
            int lag = redi[0] + 1; float val = redv[0];
            s_idx[slots] = lag; s_val[slots] = val; slots++;
            if (slots < 5 && lag < 1024) { s_idx[slots] = 2048 - lag; s_val[slots] = val; slots++; }
            v[lag - 1] = -INFINITY;
        }
        __syncthreads();
    }
    if (threadIdx.x == 0) {
        float mx = -INFINITY;
        for (int i = 0; i < 5; ++i) mx = fmaxf(mx, s_val[i]);
        float e[5], sum = 0.f;
        for (int i = 0; i < 5; ++i) { e[i] = expf(s_val[i] - mx); sum += e[i]; }
        for (int i = 0; i < 5; ++i) { selidx[b * TK + i] = s_idx[i]; selw[b * TK + i] = e[i] / sum; }
    }
}

// ---------------- conv1: 4-wave blocks, wave = 16u x 64co; LDS halo + MFMA + BN1 + GELU ----------------
__global__ __launch_bounds__(256) void k_mm1(
    const short* __restrict__ s_bf, const short* __restrict__ wtp,
    const float* __restrict__ g1, const float* __restrict__ b1,
    const float* __restrict__ m1, const float* __restrict__ v1,
    const int* __restrict__ sel, __hip_bfloat16* __restrict__ h1)
{
    int b = blockIdx.z, k = blockIdx.y;
    int p = sel[b * TK + k];
    int cyc = (TT + p - 1) / p;
    int U = cyc * p;
    int u0 = blockIdx.x * ROWS;
    if (u0 >= U) return;
    __shared__ short As[LROWS * 64];

    const short* sb = s_bf + (size_t)b * TT * TD;
    for (int q = threadIdx.x; q < LROWS * 8; q += 256) {
        int row = q >> 3, ch = (q & 7) * 8;
        int band = row / BAND, i = row - band * BAND;
        int w = u0 + (band - 1) * p - 1 + i;
        int wc = min(max(w, 0), 2 * TT - 2);
        int v = (wc < TT) ? wc : (2 * TT - 2 - wc);
        int sr = (v + p) & (TT - 1);
        short8 d = *(const short8*)(sb + (size_t)sr * TD + ch);
        int off = (row * 128 + ch * 2) ^ ((row & 7) << 4);
        *(short8*)((char*)As + off) = d;
    }
    __syncthreads();

    int lane = threadIdx.x & 63;
    int wv = threadIdx.x >> 6;
    int lr = lane & 15;
    int kg = lane >> 4;
    int lu = wv * 16 + lr;
    int u = u0 + lu;
    bool inU = (u < U);
    int r = u / p, c = u - r * p;
    bool topf = (r == 0), botf = (r == cyc - 1), leftf = (c == 0), rightf = (c == p - 1);

    f32x4 acc[4] = {};
    short8 zero = {};
    #pragma unroll
    for (int kb = 0; kb < 18; ++kb) {
        const int tap = kb >> 1, half = kb & 1;
        const int dr = tap / 3 - 1, dc = tap % 3 - 1;
        int ldsrow = (dr + 1) * BAND + lu + 1 + dc;
        int off = (ldsrow * 128 + half * 64 + kg * 16) ^ ((ldsrow & 7) << 4);
        short8 a = *(const short8*)((const char*)As + off);
        bool valid = inU
                   && !(dr == -1 && topf) && !(dr == 1 && botf)
                   && !(dc == -1 && leftf) && !(dc == 1 && rightf);
        if (!valid) a = zero;
        #pragma unroll
        for (int nt = 0; nt < 4; ++nt) {
            short8 bq = *(const short8*)(wtp + (size_t)(kb * 4 + nt) * 512 + lane * 8);
            acc[nt] = __builtin_amdgcn_mfma_f32_16x16x32_bf16(a, bq, acc[nt], 0, 0, 0);
        }
    }
    __hip_bfloat16* ho = h1 + (size_t)(b * TK + k) * (UMAX * TD);
    #pragma unroll
    for (int nt = 0; nt < 4; ++nt) {
        int co = nt * 16 + lr;
        float scale = g1[co] * rsqrtf(v1[co] + EPSBN);
        float bias = b1[co] - m1[co] * scale;
        #pragma unroll
        for (int q = 0; q < 4; ++q) {
            int uo = u0 + wv * 16 + kg * 4 + q;
            if (uo < U) {
                float z = acc[nt][q] * scale + bias;
                float ge = 0.5f * z * (1.0f + erff(z * 0.70710678118654752f));
                ho[(size_t)uo * TD + co] = __float2bfloat16(ge);
            }
        }
    }
}

// ---------------- conv2 fused over k: 4-wave blocks (wave = 16u x 16co), dbuf LDS, no atomics ----------------
__global__ __launch_bounds__(256) void k_mm2f(
    const short* __restrict__ h1, const short* __restrict__ wtp,
    const float* __restrict__ s,
    const float* __restrict__ g2, const float* __restrict__ b2,
    const float* __restrict__ m2, const float* __restrict__ v2,
    const int* __restrict__ sel, const float* __restrict__ selw,
    float* __restrict__ out)
{
    int b = blockIdx.y;
    int u0 = blockIdx.x * ROWS2;                      // < 2048
    int tid = threadIdx.x;
    __shared__ short As[2 * LROWS2 * 64];

    int lane = tid & 63, wv = tid >> 6, lr = lane & 15, kg = lane >> 4;
    int u = u0 + lr;
    const float* sb = s + (size_t)b * TT * TD;

    f32x4 accT = {};
    float gacc[4] = {0.f, 0.f, 0.f, 0.f};
    short8 sreg[2];
    short8 zero = {};

    // prologue: stage phase 0 into buffer 0
    {
        int p0 = sel[b * TK];
        const short* hb = h1 + (size_t)(b * TK) * (UMAX * TD);
        #pragma unroll
        for (int it = 0; it < 2; ++it) {
            int q = tid + it * 256;
            if (q < SH8) {
                int row = q >> 3, ch = (q & 7) * 8;
                int band = row / BAND2, i = row - band * BAND2;
                int w = u0 + (band - 1) * p0 - 1 + i;
                int wc = min(max(w, 0), UMAX - 1);
                short8 d = *(const short8*)(hb + (size_t)wc * TD + ch);
                int off = (row * 128 + ch * 2) ^ ((row & 7) << 4);
                *(short8*)((char*)As + off) = d;
            }
        }
    }
    __syncthreads();

    for (int k = 0; k < TK; ++k) {
        int p = sel[b * TK + k];
        float wk = selw[b * TK + k];
        int cyc = (TT + p - 1) / p;
        // T14: issue next phase's global loads before this phase's compute
        if (k < TK - 1) {
            int pn = sel[b * TK + k + 1];
            const short* hb = h1 + (size_t)(b * TK + k + 1) * (UMAX * TD);
            #pragma unroll
            for (int it = 0; it < 2; ++it) {
                int q = tid + it * 256;
                if (q < SH8) {
                    int row = q >> 3, ch = (q & 7) * 8;
                    int band = row / BAND2, i = row - band * BAND2;
                    int w = u0 + (band - 1) * pn - 1 + i;
                    int wc = min(max(w, 0), UMAX - 1);
                    sreg[it] = *(const short8*)(hb + (size_t)wc * TD + ch);
                }
            }
        }
        // compute phase k from buffer k&1
        const char* Ab = (const char*)As + (k & 1) * BUFB;
        int r = u / p, c = u - r * p;
        bool topf = (r == 0), botf = (r == cyc - 1), leftf = (c == 0), rightf = (c == p - 1);
        f32x4 accP[2] = {};
        #pragma unroll
        for (int kb = 0; kb < 18; ++kb) {
            const int tap = kb >> 1, half = kb & 1;
            const int dr = tap / 3 - 1, dc = tap % 3 - 1;
            int ldsrow = (dr + 1) * BAND2 + lr + 1 + dc;
            int off = (ldsrow * 128 + half * 64 + kg * 16) ^ ((ldsrow & 7) << 4);
            short8 a = *(const short8*)(Ab + off);
            bool valid = !(dr == -1 && topf) && !(dr == 1 && botf)
                       && !(dc == -1 && leftf) && !(dc == 1 && rightf);
            if (!valid) a = zero;
            short8 bq = *(const short8*)(wtp + (size_t)(kb * 4 + wv) * 512 + lane * 8);
            accP[kb & 1] = __builtin_amdgcn_mfma_f32_16x16x32_bf16(a, bq, accP[kb & 1], 0, 0, 0);
        }
        #pragma unroll
        for (int e = 0; e < 4; ++e) accT[e] += wk * (accP[0][e] + accP[1][e]);
        #pragma unroll
        for (int q = 0; q < 4; ++q) {
            int uo = u0 + kg * 4 + q;
            int sr = (uo + p) & (TT - 1);
            gacc[q] = fmaf(wk, sb[(size_t)sr * TD + wv * 16 + lr], gacc[q]);
        }
        __syncthreads();
        if (k < TK - 1) {
            char* Aw = (char*)As + ((k + 1) & 1) * BUFB;
            #pragma unroll
            for (int it = 0; it < 2; ++it) {
                int q = tid + it * 256;
                if (q < SH8) {
                    int row = q >> 3, ch = (q & 7) * 8;
                    int off = (row * 128 + ch * 2) ^ ((row & 7) << 4);
                    *(short8*)(Aw + off) = sreg[it];
                }
            }
            __syncthreads();
        }
    }

    float* ob = out + (size_t)b * TT * TD;
    int co = wv * 16 + lr;
    float scale = g2[co] * rsqrtf(v2[co] + EPSBN);
    float bias = b2[co] - m2[co] * scale;
    #pragma unroll
    for (int q = 0; q < 4; ++q) {
        int uo = u0 + kg * 4 + q;
        size_t idx = (size_t)uo * TD + co;
        ob[idx] = ob[idx] + gacc[q] + scale * accT[q] + bias;
    }
}

extern "C" void kernel_launch(void* const* d_in, const int* in_sizes, int n_in,
                              void* d_out, int out_size, void* d_ws, size_t ws_size,
                              hipStream_t stream)
{
    const float* x  = (const float*)d_in[0];
    const float* w1 = (const float*)d_in[1];
    const float* w2 = (const float*)d_in[2];
    const float* g1 = (const float*)d_in[3];
    const float* b1 = (const float*)d_in[4];
    const float* m1 = (const float*)d_in[5];
    const float* v1 = (const float*)d_in[6];
    const float* g2 = (const float*)d_in[7];
    const float* b2 = (const float*)d_in[8];
    const float* m2 = (const float*)d_in[9];
    const float* v2 = (const float*)d_in[10];

    float* ws    = (float*)d_ws;
    float* s     = ws + OFF_S;
    __hip_bfloat16* sbf = (__hip_bfloat16*)(ws + OFF_SBF);
    float* r     = ws + OFF_R;
    int*   sel   = (int*)(ws + OFF_IDX);
    float* selw  = ws + OFF_W;
    __hip_bfloat16* wt1 = (__hip_bfloat16*)(ws + OFF_WT1);
    __hip_bfloat16* wt2 = (__hip_bfloat16*)(ws + OFF_WT2);
    __hip_bfloat16* h1  = (__hip_bfloat16*)(ws + OFF_H1);
    float* out   = (float*)d_out;

    k_trend   <<<dim3(400),         dim3(256), 0, stream>>>(x, out, s, sbf, w1, w2, wt1, wt2, r);
    k_autocorr<<<dim3(64, 2, TB),   dim3(256), 0, stream>>>(s, r);
    k_topk    <<<dim3(TB),          dim3(256), 0, stream>>>(r, sel, selw);
    k_mm1     <<<dim3(64, TK, TB),  dim3(256), 0, stream>>>((const short*)sbf, (const short*)wt1,
                                                            g1, b1, m1, v1, sel, h1);
    k_mm2f    <<<dim3(128, TB),     dim3(256), 0, stream>>>((const short*)h1, (const short*)wt2, s,
                                                            g2, b2, m2, v2, sel, selw, out);
}